// Round 1
// baseline (1694.008 us; speedup 1.0000x reference)
//
#include <hip/hip_runtime.h>
#include <cstddef>

typedef _Float16 half8 __attribute__((ext_vector_type(8)));
typedef float f32x4 __attribute__((ext_vector_type(4)));

// ---------------- kernel B: per (b,t) A = I + K^T diag(q) K, Cholesky, Ainv, klc ----------------
__global__ void kb_kernel(const float* __restrict__ Kg,
                          const float* __restrict__ Qd,
                          const float* __restrict__ Q0d,
                          float* __restrict__ Ainv,
                          float* __restrict__ klc) {
  int bt = blockIdx.x;           // b*256 + t
  int t = bt & 255;
  __shared__ float Ks[128][16];
  __shared__ float qs[128];
  __shared__ float A[16][17];
  __shared__ float Lm[16][17];
  __shared__ float Li[16][17];
  __shared__ float logdet_s;
  const float* kp = Kg + (size_t)bt * 2048;
  for (int i = threadIdx.x; i < 2048; i += 128) ((float*)Ks)[i] = kp[i];
  const float* q = (t == 0) ? Q0d : Qd;
  if (threadIdx.x < 128) qs[threadIdx.x] = q[threadIdx.x];
  __syncthreads();
  for (int e = threadIdx.x; e < 256; e += 128) {
    int r = e >> 4, cc = e & 15;
    float acc = (r == cc) ? 1.0f : 0.0f;
    for (int l = 0; l < 128; ++l) acc += Ks[l][r] * qs[l] * Ks[l][cc];
    A[r][cc] = acc;
  }
  __syncthreads();
  if (threadIdx.x == 0) {
    float ld = 0.f;
    for (int j = 0; j < 16; ++j) {
      float d = A[j][j];
      for (int p = 0; p < j; ++p) d -= Lm[j][p] * Lm[j][p];
      d = sqrtf(d);
      Lm[j][j] = d;
      ld += logf(d);
      float inv = 1.0f / d;
      for (int i = j + 1; i < 16; ++i) {
        float s = A[i][j];
        for (int p = 0; p < j; ++p) s -= Lm[i][p] * Lm[j][p];
        Lm[i][j] = s * inv;
      }
    }
    logdet_s = 2.0f * ld;
  }
  __syncthreads();
  if (threadIdx.x < 16) {
    int cc = threadIdx.x;
    for (int i = 0; i < 16; ++i) {
      if (i < cc) { Li[i][cc] = 0.f; continue; }
      float s = (i == cc) ? 1.0f : 0.0f;
      for (int p = cc; p < i; ++p) s -= Lm[i][p] * Li[p][cc];
      Li[i][cc] = s / Lm[i][i];
    }
  }
  __syncthreads();
  for (int e = threadIdx.x; e < 256; e += 128) {
    int r = e >> 4, cc = e & 15;
    float s = 0.f;
    for (int i = 0; i < 16; ++i) s += Li[i][r] * Li[i][cc];
    Ainv[(size_t)bt * 256 + e] = s;
  }
  if (threadIdx.x == 0) {
    float trace = 0.f;
    for (int i = 0; i < 16; ++i)
      for (int r = 0; r < 16; ++r) trace += Li[i][r] * Li[i][r];
    klc[bt] = 0.5f * (trace - 16.0f + logdet_s);
  }
}

// ---------------- kernel C: per (t,b): z_p output + zpc = z_p - K Ainv (K^T z_p + ew) ----------------
__global__ void kc_kernel(const float* __restrict__ Kg,
                          const float* __restrict__ epsz,
                          const float* __restrict__ epsw,
                          const float* __restrict__ Qd,
                          const float* __restrict__ Q0d,
                          const float* __restrict__ Ainv,
                          float* __restrict__ out_zf,
                          float* __restrict__ out_zp) {
  int idx = blockIdx.x;
  int t = idx >> 6, b = idx & 63;
  int bt = b * 256 + t;
  __shared__ float Ks[128][16];
  __shared__ float Ai[16][16];
  __shared__ float zp[16][129];
  __shared__ float hh[16][17];
  __shared__ float ww[16][17];
  __shared__ float sq[128];
  const float* kp = Kg + (size_t)bt * 2048;
  for (int i = threadIdx.x; i < 2048; i += 256) ((float*)Ks)[i] = kp[i];
  ((float*)Ai)[threadIdx.x] = Ainv[(size_t)bt * 256 + threadIdx.x];
  const float* q = (t == 0) ? Q0d : Qd;
  if (threadIdx.x < 128) sq[threadIdx.x] = sqrtf(q[threadIdx.x]);
  __syncthreads();
  for (int i = threadIdx.x; i < 2048; i += 256) {
    int s = i >> 7, l = i & 127;
    float v = sq[l] * epsz[(((size_t)t * 16 + s) * 64 + b) * 128 + l];
    zp[s][l] = v;
    out_zp[(((size_t)s * 64 + b) * 256 + t) * 128 + l] = v;
  }
  __syncthreads();
  {
    int s = threadIdx.x >> 4, r = threadIdx.x & 15;
    float acc = epsw[(((size_t)t * 16 + s) * 64 + b) * 16 + r];
    for (int l = 0; l < 128; ++l) acc += Ks[l][r] * zp[s][l];
    hh[s][r] = acc;
  }
  __syncthreads();
  {
    int s = threadIdx.x >> 4, r = threadIdx.x & 15;
    float acc = 0.f;
    for (int j = 0; j < 16; ++j) acc += Ai[r][j] * hh[s][j];
    ww[s][r] = acc;
  }
  __syncthreads();
  for (int i = threadIdx.x; i < 2048; i += 256) {
    int s = i >> 7, l = i & 127;
    float acc = 0.f;
    for (int r = 0; r < 16; ++r) acc += Ks[l][r] * ww[s][r];
    out_zf[(((size_t)s * 64 + b) * 256 + t) * 128 + l] = zp[s][l] - acc;
  }
}

// ---------------- scan kernel: one workgroup per batch b, 16 sample-chains ----------------
__launch_bounds__(256, 1)
__global__ void kscan_kernel(const float* __restrict__ ug,
                             const float* __restrict__ kg,
                             const float* __restrict__ Kg,
                             const float* __restrict__ W1,
                             const float* __restrict__ W2,
                             const float* __restrict__ m_init,
                             const float* __restrict__ Qd,
                             const float* __restrict__ Q0d,
                             const float* __restrict__ Ainv,
                             const float* __restrict__ klc,
                             float* __restrict__ out_zf,
                             float* __restrict__ out_mf,
                             float* __restrict__ out_kl) {
  int b = blockIdx.x;
  int tid = threadIdx.x;
  int wv = tid >> 6;
  int ln = tid & 63;
  int g = ln >> 4;
  int c = ln & 15;

  __shared__ __align__(16) _Float16 svec[2][16][136];   // z (or v) hi/lo, rows = samples
  __shared__ __align__(16) _Float16 hbuf[16][264];      // tanh output, rows = samples
  __shared__ __align__(16) _Float16 ktf[4][64][8];      // B-frags: K as (128x16) B-operand
  __shared__ __align__(16) _Float16 ktTf[8][64][8];     // B-frags: K^T as (32x128) B, k>=16 zero
  __shared__ __align__(16) _Float16 wf16[16][16];
  __shared__ float aiv[16][16];
  __shared__ float h2buf[16][18];
  __shared__ float kbuf[128];
  __shared__ float qbuf[128];
  __shared__ float q0buf[128];
  __shared__ float ubuf[64];
  __shared__ float qppart[4][16];
  __shared__ float mf0[128];
  __shared__ float h2t[16];
  __shared__ float w0s[16];
  __shared__ float qp0buf[128];
  __shared__ float Ktmp[128][17];

  if (tid < 128) { qbuf[tid] = Qd[tid]; q0buf[tid] = Q0d[tid]; }

  // --- weight fragments -> registers (held whole kernel) ---
  half8 w1f[4][4];
  half8 w2f[8][2];
#pragma unroll
  for (int kt = 0; kt < 4; ++kt)
#pragma unroll
    for (int nt = 0; nt < 4; ++nt) {
      half8 v;
#pragma unroll
      for (int j = 0; j < 8; ++j)
        v[j] = (_Float16)W1[(size_t)(kt * 32 + g * 8 + j) * 256 + (wv * 64 + nt * 16 + c)];
      w1f[kt][nt] = v;
    }
#pragma unroll
  for (int kt = 0; kt < 8; ++kt)
#pragma unroll
    for (int nt = 0; nt < 2; ++nt) {
      half8 v;
#pragma unroll
      for (int j = 0; j < 8; ++j)
        v[j] = (_Float16)W2[(size_t)(kt * 32 + g * 8 + j) * 128 + (wv * 32 + nt * 16 + c)];
      w2f[kt][nt] = v;
    }

  float zreg[2][4];

  // ---------------- t = 0 (no sample dim on the mean path) ----------------
  {
    const float* K0 = Kg + (size_t)b * 524288;
    for (int i = tid; i < 2048; i += 256) Ktmp[i >> 4][i & 15] = K0[i];
    if (tid < 128) kbuf[tid] = kg[(size_t)b * 32768 + tid];
    if (tid < 64) ubuf[tid] = ug[(size_t)b * 16384 + tid];
    ((float*)aiv)[tid] = Ainv[(size_t)b * 65536 + tid];
    float kc0 = (tid == 0) ? klc[(size_t)b * 256] : 0.f;
    if (tid < 128) mf0[tid] = m_init[tid] + (tid < 64 ? ug[(size_t)b * 16384 + tid] : 0.f);
    __syncthreads();
    {
      int ch = tid >> 4, r = tid & 15;
      float acc = 0.f;
#pragma unroll
      for (int j = 0; j < 8; ++j) {
        int l = ch * 8 + j;
        acc += Ktmp[l][r] * (mf0[l] + qbuf[l] * kbuf[l]);   // v uses global Q_diag (reference closure)
      }
      h2buf[ch][r] = acc;
    }
    __syncthreads();
    if (tid < 16) {
      float s = 0.f;
      for (int ch = 0; ch < 16; ++ch) s += h2buf[ch][tid];
      h2t[tid] = s;
    }
    __syncthreads();
    if (tid < 16) {
      float s = 0.f;
      for (int q = 0; q < 16; ++q) s += aiv[tid][q] * h2t[q];
      w0s[tid] = s;
    }
    __syncthreads();
    if (tid < 128) {
      int l = tid;
      float kw = 0.f;
#pragma unroll
      for (int r = 0; r < 16; ++r) kw += Ktmp[l][r] * w0s[r];
      float gg = kbuf[l] - kw;
      float mfv = mf0[l] + q0buf[l] * gg;
      qp0buf[l] = q0buf[l] * gg * gg;
      mf0[l] = mfv;
      out_mf[(size_t)b * 32768 + l] = mfv;
    }
    __syncthreads();
    if (tid == 0) {
      float s = 0.f;
      for (int l = 0; l < 128; ++l) s += qp0buf[l];
      out_kl[(size_t)b * 256] = 0.5f * s + kc0;
    }
#pragma unroll
    for (int p = 0; p < 2; ++p)
#pragma unroll
      for (int r = 0; r < 4; ++r) {
        int col = wv * 32 + p * 16 + c;
        int srow = g * 4 + r;
        size_t oidx = (((size_t)srow * 64 + b) * 256 + 0) * 128 + col;
        float zf = mf0[col] + out_zf[oidx];
        zreg[p][r] = zf;
        out_zf[oidx] = zf;
        _Float16 zh = (_Float16)zf;
        svec[0][srow][col] = zh;
        svec[1][srow][col] = (_Float16)(zf - (float)zh);
      }
    __syncthreads();
  }

  // ---------------- main scan t = 1..255 ----------------
  for (int t = 1; t < 256; ++t) {
    // ---- staged global loads (consumed later this step; latency hidden under MLP) ----
    const float* Kt = Kg + ((size_t)b * 256 + t) * 2048;
    float zpc[2][4];
#pragma unroll
    for (int p = 0; p < 2; ++p)
#pragma unroll
      for (int r = 0; r < 4; ++r) {
        int col = wv * 32 + p * 16 + c;
        int srow = g * 4 + r;
        zpc[p][r] = out_zf[(((size_t)srow * 64 + b) * 256 + t) * 128 + col];
      }
    float kst[8];
#pragma unroll
    for (int j = 0; j < 8; ++j) kst[j] = Kt[(size_t)(wv * 32 + g * 8 + j) * 16 + c];
    float ktt[2][8];
#pragma unroll
    for (int p = 0; p < 2; ++p)
#pragma unroll
      for (int j = 0; j < 8; ++j)
        ktt[p][j] = (g * 8 + j < 16)
                        ? Kt[(size_t)((wv * 2 + p) * 16 + c) * 16 + g * 8 + j]
                        : 0.f;
    float kv = (tid < 128) ? kg[((size_t)b * 256 + t) * 128 + tid] : 0.f;
    float uv = (tid < 64) ? ug[((size_t)b * 256 + t) * 64 + tid] : 0.f;
    float av = Ainv[((size_t)b * 256 + t) * 256 + tid];
    float kcv = (tid == 0) ? klc[(size_t)b * 256 + t] : 0.f;

    // ---- mm1: h = z @ W1 (A hi/lo split) ----
    f32x4 acc1[4] = {{0,0,0,0},{0,0,0,0},{0,0,0,0},{0,0,0,0}};
#pragma unroll
    for (int kt = 0; kt < 4; ++kt) {
      half8 ah = *(const half8*)&svec[0][c][kt * 32 + g * 8];
      half8 al = *(const half8*)&svec[1][c][kt * 32 + g * 8];
#pragma unroll
      for (int nt = 0; nt < 4; ++nt) {
        acc1[nt] = __builtin_amdgcn_mfma_f32_16x16x32_f16(ah, w1f[kt][nt], acc1[nt], 0, 0, 0);
        acc1[nt] = __builtin_amdgcn_mfma_f32_16x16x32_f16(al, w1f[kt][nt], acc1[nt], 0, 0, 0);
      }
    }
    // ---- tanh -> hbuf (f16) ----
#pragma unroll
    for (int nt = 0; nt < 4; ++nt)
#pragma unroll
      for (int r = 0; r < 4; ++r) {
        float x = acc1[nt][r];
        float e = __expf(2.0f * x);
        float th = 1.0f - 2.0f / (e + 1.0f);
        hbuf[g * 4 + r][wv * 64 + nt * 16 + c] = (_Float16)th;
      }
    // ---- stage LDS part A ----
    if (tid < 128) kbuf[tid] = kv;
    if (tid < 64) ubuf[tid] = uv;
    ((float*)aiv)[tid] = av;
    __syncthreads();   // B1

    // ---- mm2: y = tanh @ W2 ----
    f32x4 acc2[2] = {{0,0,0,0},{0,0,0,0}};
#pragma unroll
    for (int kt = 0; kt < 8; ++kt) {
      half8 a = *(const half8*)&hbuf[c][kt * 32 + g * 8];
#pragma unroll
      for (int nt = 0; nt < 2; ++nt)
        acc2[nt] = __builtin_amdgcn_mfma_f32_16x16x32_f16(a, w2f[kt][nt], acc2[nt], 0, 0, 0);
    }
    // ---- m = z + y (+u), v = m + Q*k -> svec hi/lo ----
    float mreg[2][4];
#pragma unroll
    for (int p = 0; p < 2; ++p)
#pragma unroll
      for (int r = 0; r < 4; ++r) {
        int col = wv * 32 + p * 16 + c;
        float m = zreg[p][r] + acc2[p][r];
        if (col < 64) m += ubuf[col];
        mreg[p][r] = m;
        float vv = m + qbuf[col] * kbuf[col];
        _Float16 vh = (_Float16)vv;
        svec[0][g * 4 + r][col] = vh;
        svec[1][g * 4 + r][col] = (_Float16)(vv - (float)vh);
      }
    // ---- stage LDS part B (K fragments) ----
    {
      half8 kf;
#pragma unroll
      for (int j = 0; j < 8; ++j) kf[j] = (_Float16)kst[j];
      *(half8*)&ktf[wv][ln][0] = kf;
#pragma unroll
      for (int p = 0; p < 2; ++p) {
        half8 k8;
#pragma unroll
        for (int j = 0; j < 8; ++j) k8[j] = (_Float16)ktt[p][j];
        *(half8*)&ktTf[wv * 2 + p][ln][0] = k8;
      }
    }
    __syncthreads();   // B2

    // ---- h2 = v @ K (wave 0 only, hi/lo split) ----
    if (wv == 0) {
      f32x4 acch = {0, 0, 0, 0};
#pragma unroll
      for (int kt = 0; kt < 4; ++kt) {
        half8 ah = *(const half8*)&svec[0][c][kt * 32 + g * 8];
        half8 al = *(const half8*)&svec[1][c][kt * 32 + g * 8];
        half8 bf = *(const half8*)&ktf[kt][ln][0];
        acch = __builtin_amdgcn_mfma_f32_16x16x32_f16(ah, bf, acch, 0, 0, 0);
        acch = __builtin_amdgcn_mfma_f32_16x16x32_f16(al, bf, acch, 0, 0, 0);
      }
#pragma unroll
      for (int r = 0; r < 4; ++r) h2buf[g * 4 + r][c] = acch[r];
    }
    __syncthreads();   // B3

    // ---- w = Ainv h2 ----
    {
      int s = tid >> 4, r = tid & 15;
      float acc = 0.f;
#pragma unroll
      for (int q = 0; q < 16; ++q) acc += aiv[r][q] * h2buf[s][q];
      wf16[s][r] = (_Float16)acc;
    }
    __syncthreads();   // B4

    // ---- Kw = w @ K^T (K padded to 32 with zeros) ----
    half8 aw = {};
    if (g < 2) aw = *(const half8*)&wf16[c][g * 8];
    f32x4 kwa[2];
#pragma unroll
    for (int p = 0; p < 2; ++p) {
      half8 bw = *(const half8*)&ktTf[wv * 2 + p][ln][0];
      f32x4 z4 = {0, 0, 0, 0};
      kwa[p] = __builtin_amdgcn_mfma_f32_16x16x32_f16(aw, bw, z4, 0, 0, 0);
    }

    // ---- epilogue: g, m_f, z_f, outputs, next-z ----
    float qpl[4] = {0.f, 0.f, 0.f, 0.f};
    float mfsum[2];
#pragma unroll
    for (int p = 0; p < 2; ++p) {
      float msum = 0.f;
#pragma unroll
      for (int r = 0; r < 4; ++r) {
        int col = wv * 32 + p * 16 + c;
        int srow = g * 4 + r;
        float gg = kbuf[col] - kwa[p][r];
        float mf = mreg[p][r] + qbuf[col] * gg;
        float zf = mf + zpc[p][r];
        qpl[r] += qbuf[col] * gg * gg;
        msum += mf;
        zreg[p][r] = zf;
        out_zf[(((size_t)srow * 64 + b) * 256 + t) * 128 + col] = zf;
        _Float16 zh = (_Float16)zf;
        svec[0][srow][col] = zh;
        svec[1][srow][col] = (_Float16)(zf - (float)zh);
      }
      mfsum[p] = msum;
    }
#pragma unroll
    for (int p = 0; p < 2; ++p) {
      float v = mfsum[p];
      v += __shfl_xor(v, 16);
      v += __shfl_xor(v, 32);
      if (g == 0)
        out_mf[((size_t)b * 256 + t) * 128 + wv * 32 + p * 16 + c] = v * 0.0625f;
    }
#pragma unroll
    for (int r = 0; r < 4; ++r) {
      float v = qpl[r];
      v += __shfl_xor(v, 1);
      v += __shfl_xor(v, 2);
      v += __shfl_xor(v, 4);
      v += __shfl_xor(v, 8);
      if (c == 0) qppart[wv][g * 4 + r] = v;
    }
    __syncthreads();   // B5
    if (tid < 16) {
      float v = qppart[0][tid] + qppart[1][tid] + qppart[2][tid] + qppart[3][tid];
      v += __shfl_xor(v, 1);
      v += __shfl_xor(v, 2);
      v += __shfl_xor(v, 4);
      v += __shfl_xor(v, 8);
      if (tid == 0) out_kl[(size_t)b * 256 + t] = 0.5f * v * 0.0625f + kcv;
    }
  }
}

extern "C" void kernel_launch(void* const* d_in, const int* in_sizes, int n_in,
                              void* d_out, int out_size, void* d_ws, size_t ws_size,
                              hipStream_t stream) {
  (void)in_sizes; (void)n_in; (void)out_size; (void)ws_size;
  const float* u   = (const float*)d_in[0];
  const float* kk  = (const float*)d_in[1];
  const float* Kg  = (const float*)d_in[2];
  const float* epz = (const float*)d_in[3];
  const float* epw = (const float*)d_in[4];
  const float* W1  = (const float*)d_in[5];
  const float* W2  = (const float*)d_in[6];
  const float* mi  = (const float*)d_in[7];
  const float* Qd  = (const float*)d_in[8];
  const float* Q0d = (const float*)d_in[9];

  float* out_zf = (float*)d_out;                       // (S,B,T,L)
  float* out_mf = out_zf + (size_t)33554432;           // (B,T,L)
  float* out_zp = out_mf + (size_t)2097152;            // (S,B,T,L)
  float* out_kl = out_zp + (size_t)33554432;           // (B,T)

  float* Ainv = (float*)d_ws;                          // 16384 * 256 floats
  float* klc  = Ainv + (size_t)16384 * 256;            // 16384 floats

  kb_kernel<<<16384, 128, 0, stream>>>(Kg, Qd, Q0d, Ainv, klc);
  kc_kernel<<<16384, 256, 0, stream>>>(Kg, epz, epw, Qd, Q0d, Ainv, out_zf, out_zp);
  kscan_kernel<<<64, 256, 0, stream>>>(u, kk, Kg, W1, W2, mi, Qd, Q0d, Ainv, klc,
                                       out_zf, out_mf, out_kl);
}

// Round 2
// 1168.867 us; speedup vs baseline: 1.4493x; 1.4493x over previous
//
#include <hip/hip_runtime.h>
#include <cstddef>

typedef _Float16 half8 __attribute__((ext_vector_type(8)));
typedef _Float16 half4 __attribute__((ext_vector_type(4)));
typedef float f32x4 __attribute__((ext_vector_type(4)));

#define MFMA32(A, B, C) __builtin_amdgcn_mfma_f32_16x16x32_f16(A, B, C, 0, 0, 0)
#define MFMA16(A, B, C) __builtin_amdgcn_mfma_f32_16x16x16f16(A, B, C, 0, 0, 0)

// ---------------- kernel B+: per (b,t): A=I+K^T q K, chol, Ainv, klc, P, c, K^T(f16) ----------------
__global__ void kbp_kernel(const float* __restrict__ Kg,
                           const float* __restrict__ kg,
                           const float* __restrict__ Qd,
                           const float* __restrict__ Q0d,
                           float* __restrict__ Ainv,
                           float* __restrict__ klc,
                           float* __restrict__ Pg,
                           float* __restrict__ cg,
                           _Float16* __restrict__ Kt16) {
  int bt = blockIdx.x;  // b*256 + t
  int t = bt & 255;
  int tid = threadIdx.x;
  __shared__ float Ks[128][17];
  __shared__ float qs[128], qgl[128], kv[128];
  __shared__ float A[16][17];
  __shared__ float Lm[16][17];
  __shared__ float Li[16][17];
  __shared__ float Ai[16][17];
  __shared__ float Ps[128][17];
  __shared__ float yp[16][17];
  __shared__ float yv[16];
  __shared__ float logdet_s;

  const float* kp = Kg + (size_t)bt * 2048;
  for (int i = tid; i < 2048; i += 256) Ks[i >> 4][i & 15] = kp[i];
  if (tid < 128) {
    qs[tid] = (t == 0) ? Q0d[tid] : Qd[tid];
    qgl[tid] = Qd[tid];
    kv[tid] = kg[(size_t)bt * 128 + tid];
  }
  __syncthreads();
  {
    int r = tid >> 4, cc = tid & 15;
    float acc = (r == cc) ? 1.0f : 0.0f;
    for (int l = 0; l < 128; ++l) acc += Ks[l][r] * qs[l] * Ks[l][cc];
    A[r][cc] = acc;
  }
  __syncthreads();
  if (tid == 0) {
    float ld = 0.f;
    for (int j = 0; j < 16; ++j) {
      float d = A[j][j];
      for (int p = 0; p < j; ++p) d -= Lm[j][p] * Lm[j][p];
      d = sqrtf(d);
      Lm[j][j] = d;
      ld += logf(d);
      float inv = 1.0f / d;
      for (int i = j + 1; i < 16; ++i) {
        float s = A[i][j];
        for (int p = 0; p < j; ++p) s -= Lm[i][p] * Lm[j][p];
        Lm[i][j] = s * inv;
      }
    }
    logdet_s = 2.0f * ld;
  }
  __syncthreads();
  if (tid < 16) {
    int cc = tid;
    for (int i = 0; i < 16; ++i) {
      if (i < cc) { Li[i][cc] = 0.f; continue; }
      float s = (i == cc) ? 1.0f : 0.0f;
      for (int p = cc; p < i; ++p) s -= Lm[i][p] * Li[p][cc];
      Li[i][cc] = s / Lm[i][i];
    }
  }
  __syncthreads();
  // Ainv (symmetric) + y partials
  {
    int r = tid >> 4, cc = tid & 15;
    float s = 0.f;
    for (int i = 0; i < 16; ++i) s += Li[i][r] * Li[i][cc];
    Ai[r][cc] = s;
    Ainv[(size_t)bt * 256 + tid] = s;
  }
  {
    int r = tid & 15, seg = tid >> 4;
    float s = 0.f;
    for (int l = seg * 8; l < seg * 8 + 8; ++l) s += Ks[l][r] * qgl[l] * kv[l];
    yp[seg][r] = s;
  }
  __syncthreads();
  if (tid < 16) {
    float s = 0.f;
    for (int sg = 0; sg < 16; ++sg) s += yp[sg][tid];
    yv[tid] = s;
  }
  if (tid == 0) {
    float trace = 0.f;
    for (int i = 0; i < 16; ++i) trace += Ai[i][i];
    klc[bt] = 0.5f * (trace - 16.0f + logdet_s);
  }
  // P = q * (K @ Ainv)
  {
    int l = tid >> 1, r0 = (tid & 1) * 8;
    float q = qs[l];
    float pr[8];
    for (int r = 0; r < 8; ++r) {
      float s = 0.f;
      for (int j = 0; j < 16; ++j) s += Ks[l][j] * Ai[j][r0 + r];
      pr[r] = q * s;
      Ps[l][r0 + r] = pr[r];
    }
    float* pd = Pg + (size_t)bt * 2048 + l * 16 + r0;
    f32x4 v0 = {pr[0], pr[1], pr[2], pr[3]};
    f32x4 v1 = {pr[4], pr[5], pr[6], pr[7]};
    *(f32x4*)pd = v0;
    *(f32x4*)(pd + 4) = v1;
  }
  __syncthreads();
  if (tid < 128) {
    int l = tid;
    float s = qs[l] * kv[l];
    for (int r = 0; r < 16; ++r) s -= Ps[l][r] * yv[r];
    cg[(size_t)bt * 128 + l] = s;
  }
  {
    int r = tid >> 4, l0 = (tid & 15) * 8;
    half8 v;
    for (int j = 0; j < 8; ++j) v[j] = (_Float16)Ks[l0 + j][r];
    *(half8*)(Kt16 + (size_t)bt * 2048 + r * 128 + l0) = v;
  }
}

// ---------------- kernel C: per (t,b): z_p output + zpc = z_p - K Ainv (K^T z_p + ew) ----------------
__global__ void kc_kernel(const float* __restrict__ Kg,
                          const float* __restrict__ epsz,
                          const float* __restrict__ epsw,
                          const float* __restrict__ Qd,
                          const float* __restrict__ Q0d,
                          const float* __restrict__ Ainv,
                          float* __restrict__ out_zf,
                          float* __restrict__ out_zp,
                          int wzp) {
  int idx = blockIdx.x;
  int t = idx >> 6, b = idx & 63;
  int bt = b * 256 + t;
  __shared__ float Ks[128][16];
  __shared__ float Ai[16][16];
  __shared__ float zp[16][129];
  __shared__ float hh[16][17];
  __shared__ float ww[16][17];
  __shared__ float sq[128];
  const float* kp = Kg + (size_t)bt * 2048;
  for (int i = threadIdx.x; i < 2048; i += 256) ((float*)Ks)[i] = kp[i];
  ((float*)Ai)[threadIdx.x] = Ainv[(size_t)bt * 256 + threadIdx.x];
  const float* q = (t == 0) ? Q0d : Qd;
  if (threadIdx.x < 128) sq[threadIdx.x] = sqrtf(q[threadIdx.x]);
  __syncthreads();
  for (int i = threadIdx.x; i < 2048; i += 256) {
    int s = i >> 7, l = i & 127;
    float v = sq[l] * epsz[(((size_t)t * 16 + s) * 64 + b) * 128 + l];
    zp[s][l] = v;
    if (wzp) out_zp[(((size_t)s * 64 + b) * 256 + t) * 128 + l] = v;
  }
  __syncthreads();
  {
    int s = threadIdx.x >> 4, r = threadIdx.x & 15;
    float acc = epsw[(((size_t)t * 16 + s) * 64 + b) * 16 + r];
    for (int l = 0; l < 128; ++l) acc += Ks[l][r] * zp[s][l];
    hh[s][r] = acc;
  }
  __syncthreads();
  {
    int s = threadIdx.x >> 4, r = threadIdx.x & 15;
    float acc = 0.f;
    for (int j = 0; j < 16; ++j) acc += Ai[r][j] * hh[s][j];
    ww[s][r] = acc;
  }
  __syncthreads();
  for (int i = threadIdx.x; i < 2048; i += 256) {
    int s = i >> 7, l = i & 127;
    float acc = 0.f;
    for (int r = 0; r < 16; ++r) acc += Ks[l][r] * ww[s][r];
    out_zf[(((size_t)s * 64 + b) * 256 + t) * 128 + l] = zp[s][l] - acc;
  }
}

// ---------------- fallback: write out_zp after kscan (when P lives in out_zp) ----------------
__global__ void kzp_kernel(const float* __restrict__ epsz,
                           const float* __restrict__ Qd,
                           const float* __restrict__ Q0d,
                           float* __restrict__ out_zp) {
  for (size_t i = (size_t)blockIdx.x * blockDim.x + threadIdx.x; i < (size_t)33554432;
       i += (size_t)gridDim.x * blockDim.x) {
    int l = (int)(i & 127);
    int t = (int)((i >> 7) & 255);
    int sb = (int)(i >> 15);
    int s = sb >> 6, b = sb & 63;
    float q = (t == 0) ? Q0d[l] : Qd[l];
    out_zp[i] = sqrtf(q) * epsz[(((size_t)t * 16 + s) * 64 + b) * 128 + l];
  }
}

// ---------------- scan kernel: one WG per batch b; transposed (dims x samples) MFMA ----------------
__launch_bounds__(256, 1)
__global__ void kscan_kernel(const float* __restrict__ ug,
                             const float* __restrict__ W1,
                             const float* __restrict__ W2,
                             const float* __restrict__ m_init,
                             const float* __restrict__ Qd,
                             const float* __restrict__ Q0d,
                             const float* __restrict__ Pg,
                             const float* __restrict__ cg,
                             const _Float16* __restrict__ Kt16,
                             const float* __restrict__ klc,
                             float* __restrict__ out_zf,
                             float* __restrict__ out_mf,
                             float* __restrict__ out_kl) {
  const int b = blockIdx.x;
  const int tid = threadIdx.x;
  const int wv = tid >> 6;
  const int ln = tid & 63;
  const int g = ln >> 4;
  const int c = ln & 15;
  const int swz = (c & 7) << 3;  // 16B-granule XOR swizzle (element units, f16)

  __shared__ __align__(16) _Float16 svh[16 * 128];  // z hi, [sample][L]
  __shared__ __align__(16) _Float16 svl[16 * 128];  // z lo
  __shared__ __align__(16) _Float16 hb[16 * 256];   // tanh(h), [sample][hidden]
  __shared__ float h2p[4][16][18];                  // per-wave partial K^T m
  __shared__ float qpp[64];

  // ---- static A-fragments: W1^T, W2^T ----
  half8 w1f[4][4];  // [mt hidden-tile][kt L-tile]
#pragma unroll
  for (int mt = 0; mt < 4; ++mt)
#pragma unroll
    for (int kt = 0; kt < 4; ++kt) {
      half8 v;
#pragma unroll
      for (int j = 0; j < 8; ++j)
        v[j] = (_Float16)W1[(size_t)(kt * 32 + g * 8 + j) * 256 + (wv * 64 + mt * 16 + c)];
      w1f[mt][kt] = v;
    }
  half8 w2f[2][8];  // [mt L-tile][kt hidden-tile]
#pragma unroll
  for (int mt = 0; mt < 2; ++mt)
#pragma unroll
    for (int kt = 0; kt < 8; ++kt) {
      half8 v;
#pragma unroll
      for (int j = 0; j < 8; ++j)
        v[j] = (_Float16)W2[(size_t)(kt * 32 + g * 8 + j) * 128 + (wv * 32 + mt * 16 + c)];
      w2f[mt][kt] = v;
    }

  f32x4 qivQ[2], qivQ0[2];
#pragma unroll
  for (int mt = 0; mt < 2; ++mt) {
    int base = wv * 32 + mt * 16 + g * 4;
    f32x4 q = *(const f32x4*)&Qd[base];
    f32x4 q0 = *(const f32x4*)&Q0d[base];
#pragma unroll
    for (int r = 0; r < 4; ++r) {
      qivQ[mt][r] = 1.0f / q[r];
      qivQ0[mt][r] = 1.0f / q0[r];
    }
  }

  f32x4 zreg[2];   // z_f (col=sample c, rows L=32wv+16mt+4g+r)
  f32x4 m[2];      // m (same layout)
  half4 ktfrag[2]; // K^T A-frags for wave's L range
  f32x4 pA[2];     // P rows (A-frag source)
  f32x4 cvec[2];
  f32x4 zpcv[2];
  f32x4 ureg[2] = {};
  float klcv = 0.f;

  auto STAGE = [&](int t) {
    size_t bt = (size_t)b * 256 + t;
#pragma unroll
    for (int kt = 0; kt < 2; ++kt)
      ktfrag[kt] = *(const half4*)&Kt16[bt * 2048 + (size_t)c * 128 + wv * 32 + kt * 16 + g * 4];
#pragma unroll
    for (int mt = 0; mt < 2; ++mt) {
      pA[mt] = *(const f32x4*)&Pg[bt * 2048 + (size_t)(wv * 32 + mt * 16 + c) * 16 + g * 4];
      cvec[mt] = *(const f32x4*)&cg[bt * 128 + wv * 32 + mt * 16 + g * 4];
      zpcv[mt] = *(const f32x4*)&out_zf[(((size_t)c * 64 + b) * 256 + t) * 128 + wv * 32 + mt * 16 + g * 4];
      if (wv < 2) ureg[mt] = *(const f32x4*)&ug[bt * 64 + wv * 32 + mt * 16 + g * 4];
    }
    if (tid < 16) klcv = klc[bt];
  };

  auto MM3P = [&]() {  // partial h2 = K^T m over wave's 32 L
    f32x4 h2acc = {};
#pragma unroll
    for (int kt = 0; kt < 2; ++kt) {
      half4 mh, ml;
#pragma unroll
      for (int r = 0; r < 4; ++r) {
        float x = m[kt][r];
        _Float16 h = (_Float16)x;
        mh[r] = h;
        ml[r] = (_Float16)(x - (float)h);
      }
      h2acc = MFMA16(ktfrag[kt], mh, h2acc);
      h2acc = MFMA16(ktfrag[kt], ml, h2acc);
    }
#pragma unroll
    for (int r = 0; r < 4; ++r) h2p[wv][g * 4 + r][c] = h2acc[r];
  };

  auto PHASE_A = [&]() {  // h^T = W1^T z^T, tanh
    f32x4 acc1[4] = {};
#pragma unroll
    for (int kt = 0; kt < 4; ++kt) {
      half8 zh = *(const half8*)&svh[c * 128 + ((kt * 32 + g * 8) ^ swz)];
      half8 zl = *(const half8*)&svl[c * 128 + ((kt * 32 + g * 8) ^ swz)];
#pragma unroll
      for (int mt = 0; mt < 4; ++mt) {
        acc1[mt] = MFMA32(w1f[mt][kt], zh, acc1[mt]);
        acc1[mt] = MFMA32(w1f[mt][kt], zl, acc1[mt]);
      }
    }
#pragma unroll
    for (int mt = 0; mt < 4; ++mt) {
      half4 th;
#pragma unroll
      for (int r = 0; r < 4; ++r) {
        float x = acc1[mt][r];
        float e = __expf(2.0f * x);
        th[r] = (_Float16)(1.0f - 2.0f / (e + 1.0f));
      }
      *(half4*)&hb[c * 256 + ((wv * 64 + mt * 16 + g * 4) ^ swz)] = th;
    }
  };

  auto PHASE_B = [&]() {  // y^T = W2^T h^T ; m = z + y (+u); partial K^T m
    f32x4 acc2[2] = {};
#pragma unroll
    for (int kt = 0; kt < 8; ++kt) {
      half8 hf = *(const half8*)&hb[c * 256 + ((kt * 32 + g * 8) ^ swz)];
#pragma unroll
      for (int mt = 0; mt < 2; ++mt) acc2[mt] = MFMA32(w2f[mt][kt], hf, acc2[mt]);
    }
#pragma unroll
    for (int mt = 0; mt < 2; ++mt) {
      m[mt] = zreg[mt] + acc2[mt];
      if (wv < 2) m[mt] += ureg[mt];
    }
    MM3P();
  };

  auto PHASE_C = [&](int t, bool q0) {  // mDelta = P h2; epilogue
    float h2[4];
#pragma unroll
    for (int j = 0; j < 4; ++j)
      h2[j] = h2p[0][g * 4 + j][c] + h2p[1][g * 4 + j][c] + h2p[2][g * 4 + j][c] + h2p[3][g * 4 + j][c];
    half4 h2h, h2l;
#pragma unroll
    for (int j = 0; j < 4; ++j) {
      _Float16 h = (_Float16)h2[j];
      h2h[j] = h;
      h2l[j] = (_Float16)(h2[j] - (float)h);
    }
    float qpl = 0.f;
    f32x4 mfv[2];
#pragma unroll
    for (int mt = 0; mt < 2; ++mt) {
      half4 ph, pl;
#pragma unroll
      for (int r = 0; r < 4; ++r) {
        float x = pA[mt][r];
        _Float16 h = (_Float16)x;
        ph[r] = h;
        pl[r] = (_Float16)(x - (float)h);
      }
      f32x4 macc = {};
      macc = MFMA16(ph, h2h, macc);
      macc = MFMA16(ph, h2l, macc);
      macc = MFMA16(pl, h2h, macc);
      f32x4 zf4;
      f32x4 qiv = q0 ? qivQ0[mt] : qivQ[mt];
#pragma unroll
      for (int r = 0; r < 4; ++r) {
        float d = cvec[mt][r] - macc[r];
        float mf = m[mt][r] + d;
        float zf = mf + zpcv[mt][r];
        qpl += d * d * qiv[r];
        zreg[mt][r] = zf;
        zf4[r] = zf;
        mfv[mt][r] = mf;
      }
      *(f32x4*)&out_zf[(((size_t)c * 64 + b) * 256 + t) * 128 + wv * 32 + mt * 16 + g * 4] = zf4;
      half4 zh, zl;
#pragma unroll
      for (int r = 0; r < 4; ++r) {
        _Float16 h = (_Float16)zf4[r];
        zh[r] = h;
        zl[r] = (_Float16)(zf4[r] - (float)h);
      }
      *(half4*)&svh[c * 128 + ((wv * 32 + mt * 16 + g * 4) ^ swz)] = zh;
      *(half4*)&svl[c * 128 + ((wv * 32 + mt * 16 + g * 4) ^ swz)] = zl;
    }
#pragma unroll
    for (int mt = 0; mt < 2; ++mt) {
      f32x4 v = mfv[mt];
#pragma unroll
      for (int r = 0; r < 4; ++r) {
        float x = v[r];
        x += __shfl_xor(x, 1);
        x += __shfl_xor(x, 2);
        x += __shfl_xor(x, 4);
        x += __shfl_xor(x, 8);
        v[r] = x * 0.0625f;
      }
      if (c == 0)
        *(f32x4*)&out_mf[((size_t)b * 256 + t) * 128 + wv * 32 + mt * 16 + g * 4] = v;
    }
    {
      float x = qpl;
      x += __shfl_xor(x, 16);
      x += __shfl_xor(x, 32);
      if (g == 0) qpp[wv * 16 + c] = x;
    }
  };

  auto KL_FIN = [&](int t) {
    if (tid < 16) {
      float v = qpp[tid] + qpp[16 + tid] + qpp[32 + tid] + qpp[48 + tid];
      v += __shfl_xor(v, 1);
      v += __shfl_xor(v, 2);
      v += __shfl_xor(v, 4);
      v += __shfl_xor(v, 8);
      if (tid == 0) out_kl[(size_t)b * 256 + t] = 0.03125f * v + klcv;
    }
  };

  // ---------------- t = 0 ----------------
  STAGE(0);
#pragma unroll
  for (int mt = 0; mt < 2; ++mt) {
    f32x4 mi = *(const f32x4*)&m_init[wv * 32 + mt * 16 + g * 4];
    if (wv < 2) mi += ureg[mt];
    m[mt] = mi;
  }
  MM3P();
  __syncthreads();  // B2
  PHASE_C(0, true);
  __syncthreads();  // B3
  KL_FIN(0);

  // ---------------- t = 1..255 ----------------
  for (int t = 1; t < 256; ++t) {
    STAGE(t);
    PHASE_A();
    __syncthreads();  // B1
    PHASE_B();
    __syncthreads();  // B2
    PHASE_C(t, false);
    __syncthreads();  // B3
    KL_FIN(t);
  }
}

extern "C" void kernel_launch(void* const* d_in, const int* in_sizes, int n_in,
                              void* d_out, int out_size, void* d_ws, size_t ws_size,
                              hipStream_t stream) {
  (void)in_sizes; (void)n_in; (void)out_size;
  const float* u   = (const float*)d_in[0];
  const float* kk  = (const float*)d_in[1];
  const float* Kg  = (const float*)d_in[2];
  const float* epz = (const float*)d_in[3];
  const float* epw = (const float*)d_in[4];
  const float* W1  = (const float*)d_in[5];
  const float* W2  = (const float*)d_in[6];
  const float* mi  = (const float*)d_in[7];
  const float* Qd  = (const float*)d_in[8];
  const float* Q0d = (const float*)d_in[9];

  float* out_zf = (float*)d_out;                      // (S,B,T,L)
  float* out_mf = out_zf + (size_t)33554432;          // (B,T,L)
  float* out_zp = out_mf + (size_t)2097152;           // (S,B,T,L)
  float* out_kl = out_zp + (size_t)33554432;          // (B,T)

  char* ws = (char*)d_ws;
  float* Ainv    = (float*)ws;                         // 16,777,216 B
  float* klc     = (float*)(ws + 16777216);            //     65,536 B
  float* cg      = (float*)(ws + 16842752);            //  8,388,608 B
  _Float16* Kt16 = (_Float16*)(ws + 25231360);         // 67,108,864 B
  const size_t need_full = 226557952;                  // + Pg f32 134,217,728 B
  bool fb = ws_size < need_full;
  float* Pg = fb ? out_zp : (float*)(ws + 92340224);
  int wzp = fb ? 0 : 1;

  kbp_kernel<<<16384, 256, 0, stream>>>(Kg, kk, Qd, Q0d, Ainv, klc, Pg, cg, Kt16);
  kc_kernel<<<16384, 256, 0, stream>>>(Kg, epz, epw, Qd, Q0d, Ainv, out_zf, out_zp, wzp);
  kscan_kernel<<<64, 256, 0, stream>>>(u, W1, W2, mi, Qd, Q0d, Pg, cg, Kt16, klc,
                                       out_zf, out_mf, out_kl);
  if (fb) kzp_kernel<<<2048, 256, 0, stream>>>(epz, Qd, Q0d, out_zp);
}